// Round 1
// 3996.919 us; speedup vs baseline: 1.2573x; 1.2573x over previous
//
#include <hip/hip_runtime.h>
#include <cstdint>

#define D_MODEL 512
#define NHEAD   8
#define DKH     64
#define NLAYER  6
#define BATCH   16
#define SEQ     128
#define MEMS    196
#define NROWS   (BATCH*SEQ)   // 2048
#define MROWS   (BATCH*MEMS)  // 3136

typedef __attribute__((ext_vector_type(8))) short short8;
typedef __attribute__((ext_vector_type(4))) short short4v;
typedef __attribute__((ext_vector_type(4))) float floatx4;

__device__ __forceinline__ short f2bf(float f) {
    unsigned u = __builtin_bit_cast(unsigned, f);
    u += 0x7fffu + ((u >> 16) & 1u);            // RNE
    return (short)(u >> 16);
}

// ---------------- embedding + positional ----------------
__global__ __launch_bounds__(128) void embed_kernel(
    const int* __restrict__ x, const float* __restrict__ emb,
    const float* __restrict__ pos, float* __restrict__ h)
{
    const int row = blockIdx.x;
    const int s   = row & (SEQ - 1);
    const int tok = x[row];
    const int c   = threadIdx.x * 4;
    const float4 e = *(const float4*)(emb + (size_t)tok * D_MODEL + c);
    const float4 p = *(const float4*)(pos + (size_t)s   * D_MODEL + c);
    float4 o;
    o.x = e.x + p.x; o.y = e.y + p.y; o.z = e.z + p.z; o.w = e.w + p.w;
    *(float4*)(h + (size_t)row * D_MODEL + c) = o;
}

// ---------------- bf16-MFMA GEMM core: C = A(MxK,f32) @ W(KxN,f32) + bias
// Templated tile BMxBN (x32 K-step), 256 thr = 4 waves in 2x2, each wave a
// (BM/2)x(BN/2) quadrant -> (BM/32)x(BN/32) MFMA frags of 16x16x32.
// m-block is blockIdx.x (FASTEST) so consecutive blocks reuse the same W
// strip out of L2 -> kills the 8x W over-fetch seen on the logit GEMM.
// XOR chunk swizzle keeps LDS frag reads at the bank-throughput floor.
template<int BM, int BN>
__device__ __forceinline__ void gemm_core(
    const float* __restrict__ A, const float* __restrict__ W,
    const float* __restrict__ bias, float* __restrict__ C,
    int M, int K, int N, int relu)
{
    constexpr int RM  = BM / 32;           // A frags per wave
    constexpr int RN  = BN / 32;           // B frags per wave
    constexpr int TPR = 256 / BM;          // threads per A row
    constexpr int ANV = BM / 32;           // float4 A loads per thread
    constexpr int BACT = 2 * BN;           // threads active in B staging

    __shared__ __align__(16) short As[BM * 32];
    __shared__ __align__(16) short Bs[BN * 32];

    const int tid = threadIdx.x;
    const int m0 = blockIdx.x * BM, n0 = blockIdx.y * BN;
    const int lane = tid & 63;
    const int wave = tid >> 6;
    const int wm = (wave >> 1) * (BM / 2), wn = (wave & 1) * (BN / 2);
    const int fm = lane & 15;              // frag row (A) / col (B,C)
    const int fq = lane >> 4;              // k-chunk for A/B frags; row-quad for C
    const int fsw = ((fq ^ ((fm >> 2) & 3)) << 3);  // swizzled frag chunk col

    floatx4 acc[RM][RN] = {};

    // A staging: thread -> row ar, (32/TPR) consecutive k at ac
    const int ar = tid / TPR;
    const int ac = (tid % TPR) * (32 / TPR);
    const int asw = (ar >> 2) & 3;
    // B staging: thread -> 4x4 block at (kb, nb) of the 32xBN W tile
    const int kb = (tid / (BN / 4)) * 4;
    const int nb = (tid % (BN / 4)) * 4;
    const int bsw = (((kb >> 3) ^ ((nb >> 2) & 3)) << 3) + (kb & 7);

    const int arow = min(m0 + ar, M - 1);          // clamp (safety)
    const float* Ap = A + (size_t)arow * K + ac;
    const float* Wp = W + (size_t)kb * N + n0 + nb;

    for (int k0 = 0; k0 < K; k0 += 32) {
        float4 av[ANV];
        #pragma unroll
        for (int i = 0; i < ANV; ++i)
            av[i] = *(const float4*)(Ap + k0 + 4 * i);
        float4 w0 = {0,0,0,0}, w1 = {0,0,0,0}, w2 = {0,0,0,0}, w3 = {0,0,0,0};
        if (tid < BACT) {
            w0 = *(const float4*)(Wp + (size_t)(k0    ) * N);
            w1 = *(const float4*)(Wp + (size_t)(k0 + 1) * N);
            w2 = *(const float4*)(Wp + (size_t)(k0 + 2) * N);
            w3 = *(const float4*)(Wp + (size_t)(k0 + 3) * N);
        }
        __syncthreads();   // previous iteration's frag reads complete
        #pragma unroll
        for (int c = 0; c < ANV / 2; ++c) {
            const float4 lo = av[2 * c], hi = av[2 * c + 1];
            const short8 s8 = { f2bf(lo.x), f2bf(lo.y), f2bf(lo.z), f2bf(lo.w),
                                f2bf(hi.x), f2bf(hi.y), f2bf(hi.z), f2bf(hi.w) };
            *(short8*)&As[ar * 32 + ((((ac >> 3) + c) ^ asw) << 3)] = s8;
        }
        if (tid < BACT) {
            const float wt[4][4] = {{w0.x, w0.y, w0.z, w0.w},
                                    {w1.x, w1.y, w1.z, w1.w},
                                    {w2.x, w2.y, w2.z, w2.w},
                                    {w3.x, w3.y, w3.z, w3.w}};
            #pragma unroll
            for (int j = 0; j < 4; ++j) {
                const short4v bw = { f2bf(wt[0][j]), f2bf(wt[1][j]),
                                     f2bf(wt[2][j]), f2bf(wt[3][j]) };
                *(short4v*)&Bs[(nb + j) * 32 + bsw] = bw;
            }
        }
        __syncthreads();
        short8 af[RM], bfrag[RN];
        #pragma unroll
        for (int i = 0; i < RM; ++i)
            af[i] = *(const short8*)&As[(wm + i * 16 + fm) * 32 + fsw];
        #pragma unroll
        for (int j = 0; j < RN; ++j)
            bfrag[j] = *(const short8*)&Bs[(wn + j * 16 + fm) * 32 + fsw];
        #pragma unroll
        for (int i = 0; i < RM; ++i)
            #pragma unroll
            for (int j = 0; j < RN; ++j)
                acc[i][j] = __builtin_amdgcn_mfma_f32_16x16x32_bf16(
                                af[i], bfrag[j], acc[i][j], 0, 0, 0);
    }
    // epilogue: C/D layout col=lane&15, row=(lane>>4)*4+reg
    #pragma unroll
    for (int j = 0; j < RN; ++j) {
        const int col = n0 + wn + j * 16 + fm;
        const float bv = bias[col];
        #pragma unroll
        for (int i = 0; i < RM; ++i) {
            const int r0 = m0 + wm + i * 16 + fq * 4;
            #pragma unroll
            for (int r = 0; r < 4; ++r) {
                const int row = r0 + r;
                if (row < M) {
                    float v = acc[i][j][r] + bv;
                    if (relu) v = fmaxf(v, 0.f);
                    C[(size_t)row * N + col] = v;
                }
            }
        }
    }
}

// up-to-3 fused GEMMs sharing the same A (e.g. Q/K/V projections), selected
// by blockIdx.z. Launch with gridDim.z = number of live sets.
template<int BM, int BN>
__global__ __launch_bounds__(256) void mgemm(
    const float* __restrict__ A,
    const float* W0, const float* b0, float* C0,
    const float* W1, const float* b1, float* C1,
    const float* W2, const float* b2, float* C2,
    int M, int K, int N, int relu)
{
    const float* W; const float* bb; float* C;
    if (blockIdx.z == 0)      { W = W0; bb = b0; C = C0; }
    else if (blockIdx.z == 1) { W = W1; bb = b1; C = C1; }
    else                      { W = W2; bb = b2; C = C2; }
    gemm_core<BM, BN>(A, W, bb, C, M, K, N, relu);
}

// all-layer cross-attn K/V projections in ONE launch: A = memory (constant),
// blockIdx.z = 2*layer + (0:K,1:V). Weights are contiguous (L,512,512).
template<int BM, int BN>
__global__ __launch_bounds__(256) void mgemm_kv(
    const float* __restrict__ A,
    const float* Wk, const float* bk, float* Ck,
    const float* Wv, const float* bv, float* Cv,
    int M, int K, int N)
{
    const int l = blockIdx.z >> 1;
    const bool isv = blockIdx.z & 1;
    const float* W  = (isv ? Wv : Wk) + (size_t)l * K * N;
    const float* bb = (isv ? bv : bk) + (size_t)l * N;
    float* C        = (isv ? Cv : Ck) + (size_t)l * M * N;
    gemm_core<BM, BN>(A, W, bb, C, M, K, N, 0);
}

// ---------------- fused scores+softmax+PV, one block per (b, head, query row)
__global__ __launch_bounds__(256) void attn_kernel(
    const float* __restrict__ Q, const float* __restrict__ K,
    const float* __restrict__ V, float* __restrict__ O,
    int Sk, int causal)
{
    const int i  = blockIdx.x;
    const int hh = blockIdx.y;
    const int b  = blockIdx.z;
    const int tid = threadIdx.x;
    const int lane = tid & 63, wave = tid >> 6;

    __shared__ float qs[DKH];
    __shared__ float p[256];
    __shared__ float wred[8];
    __shared__ float pv[4][DKH];

    const size_t qoff = ((size_t)(b * SEQ + i)) * D_MODEL + hh * DKH;
    if (tid < DKH) qs[tid] = Q[qoff + tid];
    __syncthreads();

    float s = -1e30f;
    const bool valid = (tid < Sk) && !(causal && tid > i);
    if (valid) {
        const float* krow = K + ((size_t)(b * Sk + tid)) * D_MODEL + hh * DKH;
        float a = 0.f;
        #pragma unroll
        for (int d = 0; d < DKH; d += 4) {
            const float4 kv4 = *(const float4*)(krow + d);
            a = fmaf(qs[d],     kv4.x, a);
            a = fmaf(qs[d + 1], kv4.y, a);
            a = fmaf(qs[d + 2], kv4.z, a);
            a = fmaf(qs[d + 3], kv4.w, a);
        }
        s = a * (1.0f / 64.0f);   // ref divides by d_k, not sqrt(d_k)
    }
    // wave-level max reduce + cross-wave combine (2 barriers total)
    float m = s;
    #pragma unroll
    for (int off = 32; off > 0; off >>= 1) m = fmaxf(m, __shfl_xor(m, off));
    if (lane == 0) wred[wave] = m;
    __syncthreads();
    const float mx = fmaxf(fmaxf(wred[0], wred[1]), fmaxf(wred[2], wred[3]));
    const float e = valid ? __expf(s - mx) : 0.f;
    p[tid] = e;
    float sm = e;
    #pragma unroll
    for (int off = 32; off > 0; off >>= 1) sm += __shfl_xor(sm, off);
    if (lane == 0) wred[4 + wave] = sm;
    __syncthreads();            // covers p[] and wred[4..7]
    const float inv = 1.0f / (wred[4] + wred[5] + wred[6] + wred[7]);

    const int d = tid & (DKH - 1);
    const int c = tid >> 6;
    float a = 0.f;
    const int jend = min((c + 1) * 64, Sk);
    for (int j = c * 64; j < jend; ++j)
        a = fmaf(p[j], V[((size_t)(b * Sk + j)) * D_MODEL + hh * DKH + d], a);
    pv[c][d] = a;
    __syncthreads();
    if (tid < DKH) {
        const float o = (pv[0][tid] + pv[1][tid] + pv[2][tid] + pv[3][tid]) * inv;
        O[qoff + tid] = o;
    }
}

// ---------------- residual add + layernorm: Y = LN(X + R)*g + b
__global__ __launch_bounds__(256) void ln_kernel(
    const float* __restrict__ X, const float* __restrict__ R,
    const float* __restrict__ g, const float* __restrict__ bb,
    float* __restrict__ Y, float eps)
{
    const int row = blockIdx.x;
    const int tid = threadIdx.x;
    const int lane = tid & 63, wave = tid >> 6;
    __shared__ float wred[8];
    const size_t base = (size_t)row * D_MODEL;
    const float x0 = X[base + tid]       + R[base + tid];
    const float x1 = X[base + 256 + tid] + R[base + 256 + tid];
    float sm = x0 + x1;
    #pragma unroll
    for (int off = 32; off > 0; off >>= 1) sm += __shfl_xor(sm, off);
    if (lane == 0) wred[wave] = sm;
    __syncthreads();
    const float mu = (wred[0] + wred[1] + wred[2] + wred[3]) * (1.0f / D_MODEL);
    const float d0 = x0 - mu, d1 = x1 - mu;
    float vs = d0 * d0 + d1 * d1;
    #pragma unroll
    for (int off = 32; off > 0; off >>= 1) vs += __shfl_xor(vs, off);
    if (lane == 0) wred[4 + wave] = vs;
    __syncthreads();
    const float var  = (wred[4] + wred[5] + wred[6] + wred[7]) * (1.0f / D_MODEL);
    const float rstd = rsqrtf(var + eps);
    Y[base + tid]       = d0 * rstd * g[tid]       + bb[tid];
    Y[base + 256 + tid] = d1 * rstd * g[256 + tid] + bb[256 + tid];
}

extern "C" void kernel_launch(void* const* d_in, const int* in_sizes, int n_in,
                              void* d_out, int out_size, void* d_ws, size_t ws_size,
                              hipStream_t stream)
{
    const int*   x      = (const int*)  d_in[0];
    const float* memory = (const float*)d_in[1];
    // d_in[2] = mask — exactly causal tril; handled analytically
    const float* emb    = (const float*)d_in[3];
    const float* pos    = (const float*)d_in[4];
    const float* sa_qw  = (const float*)d_in[5];
    const float* sa_kw  = (const float*)d_in[6];
    const float* sa_vw  = (const float*)d_in[7];
    const float* sa_ow  = (const float*)d_in[8];
    const float* sa_qb  = (const float*)d_in[9];
    const float* sa_kb  = (const float*)d_in[10];
    const float* sa_vb  = (const float*)d_in[11];
    const float* sa_ob  = (const float*)d_in[12];
    const float* sa_lnb = (const float*)d_in[13];
    const float* sa_lng = (const float*)d_in[14];
    const float* ca_qw  = (const float*)d_in[15];
    const float* ca_kw  = (const float*)d_in[16];
    const float* ca_vw  = (const float*)d_in[17];
    const float* ca_ow  = (const float*)d_in[18];
    const float* ca_qb  = (const float*)d_in[19];
    const float* ca_kb  = (const float*)d_in[20];
    const float* ca_vb  = (const float*)d_in[21];
    const float* ca_ob  = (const float*)d_in[22];
    const float* ca_lnb = (const float*)d_in[23];
    const float* ca_lng = (const float*)d_in[24];
    const float* ff_w1  = (const float*)d_in[25];
    const float* ff_b1  = (const float*)d_in[26];
    const float* ff_w2  = (const float*)d_in[27];
    const float* ff_b2  = (const float*)d_in[28];
    const float* ff_lng = (const float*)d_in[29];
    const float* ff_lnb = (const float*)d_in[30];
    const float* logit_w= (const float*)d_in[31];
    const float* logit_b= (const float*)d_in[32];

    float* out = (float*)d_out;
    float* h    = (float*)d_ws;                         // 2048x512 (persistent)
    float* q    = out;                                  // scratch inside d_out
    float* k    = q    + (size_t)NROWS * D_MODEL;
    float* v    = k    + (size_t)MROWS * D_MODEL;
    float* att  = v    + (size_t)MROWS * D_MODEL;
    float* proj = att  + (size_t)NROWS * D_MODEL;
    float* ffh  = proj + (size_t)NROWS * D_MODEL;       // 2048x2048
    float* kall = ffh  + (size_t)NROWS * 2048;          // 6 x 3136x512
    float* vall = kall + (size_t)NLAYER * MROWS * D_MODEL;
    const size_t KVOFF = (size_t)MROWS * D_MODEL;

    embed_kernel<<<NROWS, 128, 0, stream>>>(x, emb, pos, h);

    // all 6 layers' cross-attn K/V projections from constant `memory`, one launch
    mgemm_kv<64,64><<<dim3(MROWS/64, 8, 2*NLAYER), 256, 0, stream>>>(
        memory, ca_kw, ca_kb, kall, ca_vw, ca_vb, vall, MROWS, 512, 512);

    const dim3 gattn(SEQ, NHEAD, BATCH);
    const dim3 g512(NROWS/64, 8, 1);       // 256 blocks
    const dim3 gqkv(NROWS/64, 8, 3);       // 768 blocks

    for (int l = 0; l < NLAYER; ++l) {
        const size_t w2 = (size_t)l * D_MODEL * D_MODEL;
        const size_t b1 = (size_t)l * D_MODEL;
        // ---- masked self-attention ----
        mgemm<64,64><<<gqkv, 256, 0, stream>>>(h,
            sa_qw + w2, sa_qb + b1, q,
            sa_kw + w2, sa_kb + b1, k,
            sa_vw + w2, sa_vb + b1, v, NROWS, 512, 512, 0);
        attn_kernel<<<gattn, 256, 0, stream>>>(q, k, v, att, SEQ, 1);
        mgemm<64,64><<<g512, 256, 0, stream>>>(att,
            sa_ow + w2, sa_ob + b1, proj,
            sa_ow + w2, sa_ob + b1, proj,
            sa_ow + w2, sa_ob + b1, proj, NROWS, 512, 512, 0);
        ln_kernel<<<NROWS, 256, 0, stream>>>(proj, h, sa_lng + b1, sa_lnb + b1, h, 1e-8f);
        // ---- cross-attention over memory (K/V precomputed) ----
        mgemm<64,64><<<g512, 256, 0, stream>>>(h,
            ca_qw + w2, ca_qb + b1, q,
            ca_qw + w2, ca_qb + b1, q,
            ca_qw + w2, ca_qb + b1, q, NROWS, 512, 512, 0);
        attn_kernel<<<gattn, 256, 0, stream>>>(q, kall + (size_t)l * KVOFF,
                                               vall + (size_t)l * KVOFF, att, MEMS, 0);
        mgemm<64,64><<<g512, 256, 0, stream>>>(att,
            ca_ow + w2, ca_ob + b1, proj,
            ca_ow + w2, ca_ob + b1, proj,
            ca_ow + w2, ca_ob + b1, proj, NROWS, 512, 512, 0);
        ln_kernel<<<NROWS, 256, 0, stream>>>(proj, h, ca_lng + b1, ca_lnb + b1, h, 1e-8f);
        // ---- feed-forward ----
        mgemm<64,64><<<dim3(NROWS/64, 2048/64, 1), 256, 0, stream>>>(h,
            ff_w1 + (size_t)l * D_MODEL * 2048, ff_b1 + (size_t)l * 2048, ffh,
            ff_w1 + (size_t)l * D_MODEL * 2048, ff_b1 + (size_t)l * 2048, ffh,
            ff_w1 + (size_t)l * D_MODEL * 2048, ff_b1 + (size_t)l * 2048, ffh,
            NROWS, 512, 2048, 1);
        mgemm<64,64><<<g512, 256, 0, stream>>>(ffh,
            ff_w2 + (size_t)l * 2048 * D_MODEL, ff_b2 + b1, proj,
            ff_w2 + (size_t)l * 2048 * D_MODEL, ff_b2 + b1, proj,
            ff_w2 + (size_t)l * 2048 * D_MODEL, ff_b2 + b1, proj,
            NROWS, 2048, 512, 0);
        ln_kernel<<<NROWS, 256, 0, stream>>>(proj, h, ff_lng + b1, ff_lnb + b1, h, 1e-6f);
    }
    // ---- logits: m-fastest grid -> W strips L2-resident, A L3-resident ----
    mgemm<128,128><<<dim3(NROWS/128, 32000/128, 1), 256, 0, stream>>>(h,
        logit_w, logit_b, out,
        logit_w, logit_b, out,
        logit_w, logit_b, out, NROWS, 512, 32000, 0);
}

// Round 3
// 3528.148 us; speedup vs baseline: 1.4244x; 1.1329x over previous
//
#include <hip/hip_runtime.h>
#include <cstdint>

#define D_MODEL 512
#define NHEAD   8
#define DKH     64
#define NLAYER  6
#define BATCH   16
#define SEQ     128
#define MEMS    196
#define NROWS   (BATCH*SEQ)   // 2048
#define MROWS   (BATCH*MEMS)  // 3136
#define SQW     (512*512)

typedef __attribute__((ext_vector_type(8))) short short8;
typedef __attribute__((ext_vector_type(4))) short short4v;
typedef __attribute__((ext_vector_type(4))) float floatx4;

__device__ __forceinline__ short f2bf(float f) {
    unsigned u = __builtin_bit_cast(unsigned, f);
    u += 0x7fffu + ((u >> 16) & 1u);            // RNE
    return (short)(u >> 16);
}

// async global->LDS, 16B per lane, dest = wave-uniform base + lane*16
#define GLD16(g, l) __builtin_amdgcn_global_load_lds( \
    (const __attribute__((address_space(1))) void*)(g), \
    (__attribute__((address_space(3))) void*)(l), 16, 0, 0)

// ---------------- embedding + positional (fp32 + bf16 mirror) ----------------
__global__ __launch_bounds__(128) void embed_kernel(
    const int* __restrict__ x, const float* __restrict__ emb,
    const float* __restrict__ pos, float* __restrict__ h, ushort* __restrict__ hb)
{
    const int row = blockIdx.x;
    const int s   = row & (SEQ - 1);
    const int tok = x[row];
    const int c   = threadIdx.x * 4;
    const float4 e = *(const float4*)(emb + (size_t)tok * D_MODEL + c);
    const float4 p = *(const float4*)(pos + (size_t)s   * D_MODEL + c);
    float4 o;
    o.x = e.x + p.x; o.y = e.y + p.y; o.z = e.z + p.z; o.w = e.w + p.w;
    *(float4*)(h + (size_t)row * D_MODEL + c) = o;
    const short4v ob = { f2bf(o.x), f2bf(o.y), f2bf(o.z), f2bf(o.w) };
    *(short4v*)(hb + (size_t)row * D_MODEL + c) = ob;
}

// ---------------- weight transpose+convert: Out[n][k] = bf16(In[k][n]) -------
__device__ __forceinline__ void wtrans_tile(
    const float* __restrict__ In, ushort* __restrict__ Out,
    int K, int N, int tk, int tx)
{
    __shared__ ushort t[32][33];
    const int tid = threadIdx.x;
    const int r  = tid >> 3;            // 0..31
    const int c4 = (tid & 7) << 2;      // 0,4,..,28
    const float4 v = *(const float4*)(In + (size_t)(tk * 32 + r) * N + tx * 32 + c4);
    t[c4 + 0][r] = (ushort)f2bf(v.x);
    t[c4 + 1][r] = (ushort)f2bf(v.y);
    t[c4 + 2][r] = (ushort)f2bf(v.z);
    t[c4 + 3][r] = (ushort)f2bf(v.w);
    __syncthreads();
    const short4v o = { (short)t[r][c4], (short)t[r][c4 + 1],
                        (short)t[r][c4 + 2], (short)t[r][c4 + 3] };
    *(short4v*)(Out + (size_t)(tx * 32 + r) * K + tk * 32 + c4) = o;
}

struct Ptr8 { const float* p[8]; };

// all 8 square (512x512) weight families x 6 layers -> wsq[mat][512][512]
__global__ __launch_bounds__(256) void wtrans_sq(Ptr8 ps, ushort* __restrict__ out)
{
    const int mat = blockIdx.y;              // 0..47
    const int a = mat / 6, l = mat - a * 6;
    const float* In = ps.p[a] + (size_t)l * SQW;
    ushort* Out = out + (size_t)mat * SQW;
    const int tx = blockIdx.x & 15, tk = blockIdx.x >> 4;
    wtrans_tile(In, Out, 512, 512, tk, tx);
}

__global__ __launch_bounds__(256) void wtrans_rect(
    const float* __restrict__ in, ushort* __restrict__ out, int K, int N)
{
    const float* In = in + (size_t)blockIdx.z * K * N;
    ushort* Out = out + (size_t)blockIdx.z * K * N;
    const int ntx = N >> 5;
    const int tx = blockIdx.x % ntx, tk = blockIdx.x / ntx;
    wtrans_tile(In, Out, K, N, tk, tx);
}

// fp32 -> bf16 elementwise (memory operand)
__global__ __launch_bounds__(256) void convb(
    const float* __restrict__ in, ushort* __restrict__ out)
{
    const size_t i = ((size_t)blockIdx.x * 256 + threadIdx.x) * 8;
    const float4 a = *(const float4*)(in + i);
    const float4 b = *(const float4*)(in + i + 4);
    const short8 o = { f2bf(a.x), f2bf(a.y), f2bf(a.z), f2bf(a.w),
                       f2bf(b.x), f2bf(b.y), f2bf(b.z), f2bf(b.w) };
    *(short8*)(out + i) = o;
}

// ---------------- bf16 GEMM: C = A(MxK,bf16) @ WT(NxK,bf16)^T + bias ---------
// global_load_lds staging (16B/lane, source pre-swizzled), double-buffered LDS,
// ONE barrier per K-step (stage next || compute current). 256 thr = 4 waves.
template<int BM, int BN>
__device__ __forceinline__ void bgemm_core(
    const ushort* __restrict__ A, const ushort* __restrict__ WT,
    const float* __restrict__ bias, float* __restrict__ Cf,
    ushort* __restrict__ Cb, int M, int K, int N, int relu)
{
    constexpr int WM = (BM >= 64) ? 2 : 1;
    constexpr int WN = 4 / WM;
    constexpr int RM = BM / (WM * 16);
    constexpr int RN = BN / (WN * 16);
    constexpr int SA = BM / 16;          // 1KB stage slots for A
    constexpr int SB = BN / 16;
    constexpr int ST = SA + SB;

    __shared__ __align__(16) ushort As[2][BM * 32];
    __shared__ __align__(16) ushort Bs[2][BN * 32];

    const int tid  = threadIdx.x;
    const int lane = tid & 63, wave = tid >> 6;
    const int m0 = blockIdx.x * BM, n0 = blockIdx.y * BN;
    const int wm = (wave % WM) * (16 * RM);
    const int wn = (wave / WM) * (16 * RN);
    const int fm = lane & 15, fq = lane >> 4;
    const int rdoff = ((fq ^ ((fm >> 2) & 3)) << 3);     // swizzled read chunk

    // staging: lane -> row lane>>2 in 16-row group, source chunk pre-swizzled
    // (write permutation == read permutation, both keyed on (row>>2)&3)
    const int srow = lane >> 2;
    const int soff = (((lane & 3) ^ ((lane >> 4) & 3)) << 3);

    floatx4 acc[RM][RN] = {};

    auto stage = [&](int buf, int k0) {
        #pragma unroll
        for (int s = 0; s < ST; ++s) {
            if ((s & 3) != wave) continue;     // wave-uniform predicate
            if (s < SA)
                GLD16(A + (size_t)(m0 + s * 16 + srow) * K + k0 + soff,
                      &As[buf][s * 512]);
            else
                GLD16(WT + (size_t)(n0 + (s - SA) * 16 + srow) * K + k0 + soff,
                      &Bs[buf][(s - SA) * 512]);
        }
    };

    stage(0, 0);
    __syncthreads();                       // drains vmcnt(0)
    const int NT = K >> 5;
    int cur = 0;
    for (int t = 0; t < NT; ++t) {
        if (t + 1 < NT) stage(cur ^ 1, (t + 1) << 5);
        short8 af[RM], bfr[RN];
        #pragma unroll
        for (int i = 0; i < RM; ++i)
            af[i] = *(const short8*)&As[cur][(wm + i * 16 + fm) * 32 + rdoff];
        #pragma unroll
        for (int j = 0; j < RN; ++j)
            bfr[j] = *(const short8*)&Bs[cur][(wn + j * 16 + fm) * 32 + rdoff];
        #pragma unroll
        for (int i = 0; i < RM; ++i)
            #pragma unroll
            for (int j = 0; j < RN; ++j)
                acc[i][j] = __builtin_amdgcn_mfma_f32_16x16x32_bf16(
                                af[i], bfr[j], acc[i][j], 0, 0, 0);
        __syncthreads();                   // stage complete + frag reads done
        cur ^= 1;
    }

    // epilogue: C/D layout col=lane&15, row=(lane>>4)*4+reg
    #pragma unroll
    for (int j = 0; j < RN; ++j) {
        const int col = n0 + wn + j * 16 + fm;
        const float bv = bias[col];
        #pragma unroll
        for (int i = 0; i < RM; ++i) {
            const int r0 = m0 + wm + i * 16 + fq * 4;
            #pragma unroll
            for (int r = 0; r < 4; ++r) {
                float v = acc[i][j][r] + bv;
                if (relu) v = fmaxf(v, 0.f);
                const size_t idx = (size_t)(r0 + r) * N + col;
                if (Cf) Cf[idx] = v;
                if (Cb) Cb[idx] = (ushort)f2bf(v);
            }
        }
    }
}

// up-to-3 fused GEMMs sharing A, selected by blockIdx.z
template<int BM, int BN>
__global__ __launch_bounds__(256) void bgemm(
    const ushort* __restrict__ A,
    const ushort* W0, const float* b0, float* F0, ushort* O0,
    const ushort* W1, const float* b1, float* F1, ushort* O1,
    const ushort* W2, const float* b2, float* F2, ushort* O2,
    int M, int K, int N, int relu)
{
    const ushort* W; const float* bb; float* F; ushort* Ob;
    if (blockIdx.z == 0)      { W = W0; bb = b0; F = F0; Ob = O0; }
    else if (blockIdx.z == 1) { W = W1; bb = b1; F = F1; Ob = O1; }
    else                      { W = W2; bb = b2; F = F2; Ob = O2; }
    bgemm_core<BM, BN>(A, W, bb, F, Ob, M, K, N, relu);
}

// all-layer cross-attn K/V projections in ONE launch (z = 2*layer + isV)
template<int BM, int BN>
__global__ __launch_bounds__(256) void bgemm_kv(
    const ushort* __restrict__ A,
    const ushort* Wk, const float* bk, float* Ck,
    const ushort* Wv, const float* bv, float* Cv,
    int M, int K, int N)
{
    const int l = blockIdx.z >> 1;
    const bool isv = blockIdx.z & 1;
    const ushort* W = (isv ? Wv : Wk) + (size_t)l * K * N;
    const float* bb = (isv ? bv : bk) + (size_t)l * N;
    float* C        = (isv ? Cv : Ck) + (size_t)l * M * N;
    bgemm_core<BM, BN>(A, W, bb, C, (ushort*)nullptr, M, K, N, 0);
}

// ---------------- round-1-proven fp32 GEMM (logit fallback if ws small) ------
__global__ __launch_bounds__(256) void mgemm_f32(
    const float* __restrict__ A, const float* __restrict__ W,
    const float* __restrict__ bias, float* __restrict__ C,
    int M, int K, int N, int relu)
{
    constexpr int BM = 128, BN = 128;
    constexpr int RM = BM / 32, RN = BN / 32;
    constexpr int TPR = 256 / BM;
    constexpr int ANV = BM / 32;
    constexpr int BACT = 2 * BN;

    __shared__ __align__(16) short As[BM * 32];
    __shared__ __align__(16) short Bs[BN * 32];

    const int tid = threadIdx.x;
    const int m0 = blockIdx.x * BM, n0 = blockIdx.y * BN;
    const int lane = tid & 63;
    const int wave = tid >> 6;
    const int wm = (wave >> 1) * (BM / 2), wn = (wave & 1) * (BN / 2);
    const int fm = lane & 15;
    const int fq = lane >> 4;
    const int fsw = ((fq ^ ((fm >> 2) & 3)) << 3);

    floatx4 acc[RM][RN] = {};

    const int ar = tid / TPR;
    const int ac = (tid % TPR) * (32 / TPR);
    const int asw = (ar >> 2) & 3;
    const int kb = (tid / (BN / 4)) * 4;
    const int nb = (tid % (BN / 4)) * 4;
    const int bsw = (((kb >> 3) ^ ((nb >> 2) & 3)) << 3) + (kb & 7);

    const int arow = min(m0 + ar, M - 1);
    const float* Ap = A + (size_t)arow * K + ac;
    const float* Wp = W + (size_t)kb * N + n0 + nb;

    for (int k0 = 0; k0 < K; k0 += 32) {
        float4 av[ANV];
        #pragma unroll
        for (int i = 0; i < ANV; ++i)
            av[i] = *(const float4*)(Ap + k0 + 4 * i);
        float4 w0 = {0,0,0,0}, w1 = {0,0,0,0}, w2 = {0,0,0,0}, w3 = {0,0,0,0};
        if (tid < BACT) {
            w0 = *(const float4*)(Wp + (size_t)(k0    ) * N);
            w1 = *(const float4*)(Wp + (size_t)(k0 + 1) * N);
            w2 = *(const float4*)(Wp + (size_t)(k0 + 2) * N);
            w3 = *(const float4*)(Wp + (size_t)(k0 + 3) * N);
        }
        __syncthreads();
        #pragma unroll
        for (int c = 0; c < ANV / 2; ++c) {
            const float4 lo = av[2 * c], hi = av[2 * c + 1];
            const short8 s8 = { f2bf(lo.x), f2bf(lo.y), f2bf(lo.z), f2bf(lo.w),
                                f2bf(hi.x), f2bf(hi.y), f2bf(hi.z), f2bf(hi.w) };
            *(short8*)&As[ar * 32 + ((((ac >> 3) + c) ^ asw) << 3)] = s8;
        }
        if (tid < BACT) {
            const float wt[4][4] = {{w0.x, w0.y, w0.z, w0.w},
                                    {w1.x, w1.y, w1.z, w1.w},
                                    {w2.x, w2.y, w2.z, w2.w},
                                    {w3.x, w3.y, w3.z, w3.w}};
            #pragma unroll
            for (int j = 0; j < 4; ++j) {
                const short4v bw = { f2bf(wt[0][j]), f2bf(wt[1][j]),
                                     f2bf(wt[2][j]), f2bf(wt[3][j]) };
                *(short4v*)&Bs[(nb + j) * 32 + bsw] = bw;
            }
        }
        __syncthreads();
        short8 af[RM], bfrag[RN];
        #pragma unroll
        for (int i = 0; i < RM; ++i)
            af[i] = *(const short8*)&As[(wm + i * 16 + fm) * 32 + fsw];
        #pragma unroll
        for (int j = 0; j < RN; ++j)
            bfrag[j] = *(const short8*)&Bs[(wn + j * 16 + fm) * 32 + fsw];
        #pragma unroll
        for (int i = 0; i < RM; ++i)
            #pragma unroll
            for (int j = 0; j < RN; ++j)
                acc[i][j] = __builtin_amdgcn_mfma_f32_16x16x32_bf16(
                                af[i], bfrag[j], acc[i][j], 0, 0, 0);
    }
    #pragma unroll
    for (int j = 0; j < RN; ++j) {
        const int col = n0 + wn + j * 16 + fm;
        const float bv = bias[col];
        #pragma unroll
        for (int i = 0; i < RM; ++i) {
            const int r0 = m0 + wm + i * 16 + fq * 4;
            #pragma unroll
            for (int r = 0; r < 4; ++r) {
                const int row = r0 + r;
                if (row < M) {
                    float v = acc[i][j][r] + bv;
                    if (relu) v = fmaxf(v, 0.f);
                    C[(size_t)row * N + col] = v;
                }
            }
        }
    }
}

// ---------------- fused scores+softmax+PV, one block per (b, head, query row)
__global__ __launch_bounds__(256) void attn_kernel(
    const float* __restrict__ Q, const float* __restrict__ K,
    const float* __restrict__ V, ushort* __restrict__ O,
    int Sk, int causal)
{
    const int i  = blockIdx.x;
    const int hh = blockIdx.y;
    const int b  = blockIdx.z;
    const int tid = threadIdx.x;
    const int lane = tid & 63, wave = tid >> 6;

    __shared__ float qs[DKH];
    __shared__ float p[256];
    __shared__ float wred[8];
    __shared__ float pv[4][DKH];

    const size_t qoff = ((size_t)(b * SEQ + i)) * D_MODEL + hh * DKH;
    if (tid < DKH) qs[tid] = Q[qoff + tid];
    __syncthreads();

    float s = -1e30f;
    const bool valid = (tid < Sk) && !(causal && tid > i);
    if (valid) {
        const float* krow = K + ((size_t)(b * Sk + tid)) * D_MODEL + hh * DKH;
        float a = 0.f;
        #pragma unroll
        for (int d = 0; d < DKH; d += 4) {
            const float4 kv4 = *(const float4*)(krow + d);
            a = fmaf(qs[d],     kv4.x, a);
            a = fmaf(qs[d + 1], kv4.y, a);
            a = fmaf(qs[d + 2], kv4.z, a);
            a = fmaf(qs[d + 3], kv4.w, a);
        }
        s = a * (1.0f / 64.0f);   // ref divides by d_k, not sqrt(d_k)
    }
    float m = s;
    #pragma unroll
    for (int off = 32; off > 0; off >>= 1) m = fmaxf(m, __shfl_xor(m, off));
    if (lane == 0) wred[wave] = m;
    __syncthreads();
    const float mx = fmaxf(fmaxf(wred[0], wred[1]), fmaxf(wred[2], wred[3]));
    const float e = valid ? __expf(s - mx) : 0.f;
    p[tid] = e;
    float sm = e;
    #pragma unroll
    for (int off = 32; off > 0; off >>= 1) sm += __shfl_xor(sm, off);
    if (lane == 0) wred[4 + wave] = sm;
    __syncthreads();            // covers p[] and wred[4..7]
    const float inv = 1.0f / (wred[4] + wred[5] + wred[6] + wred[7]);

    const int d = tid & (DKH - 1);
    const int c = tid >> 6;
    float a = 0.f;
    const int jend = min((c + 1) * 64, Sk);
    for (int j = c * 64; j < jend; ++j)
        a = fmaf(p[j], V[((size_t)(b * Sk + j)) * D_MODEL + hh * DKH + d], a);
    pv[c][d] = a;
    __syncthreads();
    if (tid < DKH) {
        const float o = (pv[0][tid] + pv[1][tid] + pv[2][tid] + pv[3][tid]) * inv;
        O[qoff + tid] = (ushort)f2bf(o);
    }
}

// ---------------- residual add + layernorm: Y = LN(X + R)*g + b (+bf16 mirror)
__global__ __launch_bounds__(256) void ln_kernel(
    const float* __restrict__ X, const float* __restrict__ R,
    const float* __restrict__ g, const float* __restrict__ bb,
    float* __restrict__ Y, ushort* __restrict__ Yb, float eps)
{
    const int row = blockIdx.x;
    const int tid = threadIdx.x;
    const int lane = tid & 63, wave = tid >> 6;
    __shared__ float wred[8];
    const size_t base = (size_t)row * D_MODEL;
    const float x0 = X[base + tid]       + R[base + tid];
    const float x1 = X[base + 256 + tid] + R[base + 256 + tid];
    float sm = x0 + x1;
    #pragma unroll
    for (int off = 32; off > 0; off >>= 1) sm += __shfl_xor(sm, off);
    if (lane == 0) wred[wave] = sm;
    __syncthreads();
    const float mu = (wred[0] + wred[1] + wred[2] + wred[3]) * (1.0f / D_MODEL);
    const float d0 = x0 - mu, d1 = x1 - mu;
    float vs = d0 * d0 + d1 * d1;
    #pragma unroll
    for (int off = 32; off > 0; off >>= 1) vs += __shfl_xor(vs, off);
    if (lane == 0) wred[4 + wave] = vs;
    __syncthreads();
    const float var  = (wred[4] + wred[5] + wred[6] + wred[7]) * (1.0f / D_MODEL);
    const float rstd = rsqrtf(var + eps);
    const float y0 = d0 * rstd * g[tid]       + bb[tid];
    const float y1 = d1 * rstd * g[256 + tid] + bb[256 + tid];
    Y[base + tid]       = y0;
    Y[base + 256 + tid] = y1;
    Yb[base + tid]       = (ushort)f2bf(y0);
    Yb[base + 256 + tid] = (ushort)f2bf(y1);
}

extern "C" void kernel_launch(void* const* d_in, const int* in_sizes, int n_in,
                              void* d_out, int out_size, void* d_ws, size_t ws_size,
                              hipStream_t stream)
{
    const int*   x      = (const int*)  d_in[0];
    const float* memory = (const float*)d_in[1];
    // d_in[2] = mask — exactly causal tril; handled analytically
    const float* emb    = (const float*)d_in[3];
    const float* pos    = (const float*)d_in[4];
    const float* sa_qw  = (const float*)d_in[5];
    const float* sa_kw  = (const float*)d_in[6];
    const float* sa_vw  = (const float*)d_in[7];
    const float* sa_ow  = (const float*)d_in[8];
    const float* sa_qb  = (const float*)d_in[9];
    const float* sa_kb  = (const float*)d_in[10];
    const float* sa_vb  = (const float*)d_in[11];
    const float* sa_ob  = (const float*)d_in[12];
    const float* sa_lnb = (const float*)d_in[13];
    const float* sa_lng = (const float*)d_in[14];
    const float* ca_qw  = (const float*)d_in[15];
    const float* ca_kw  = (const float*)d_in[16];
    const float* ca_vw  = (const float*)d_in[17];
    const float* ca_ow  = (const float*)d_in[18];
    const float* ca_qb  = (const float*)d_in[19];
    const float* ca_kb  = (const float*)d_in[20];
    const float* ca_vb  = (const float*)d_in[21];
    const float* ca_ob  = (const float*)d_in[22];
    const float* ca_lnb = (const float*)d_in[23];
    const float* ca_lng = (const float*)d_in[24];
    const float* ff_w1  = (const float*)d_in[25];
    const float* ff_b1  = (const float*)d_in[26];
    const float* ff_w2  = (const float*)d_in[27];
    const float* ff_b2  = (const float*)d_in[28];
    const float* ff_lng = (const float*)d_in[29];
    const float* ff_lnb = (const float*)d_in[30];
    const float* logit_w= (const float*)d_in[31];
    const float* logit_b= (const float*)d_in[32];

    float* out = (float*)d_out;
    const size_t ROWB = (size_t)NROWS * D_MODEL;            // 1M elems

    // ---- d_ws: h (proven) + optionally {hb, wlogT} (read by final logit) ----
    const size_t WS_H    = ROWB * 4;                        // 4 MB
    const size_t WS_HB   = ROWB * 2;                        // 2 MB
    const size_t WS_WLOG = 512ull * 32000 * 2;              // 32.8 MB
    const bool wsBig = ws_size >= WS_H + WS_HB + WS_WLOG + 1024;

    char* wp = (char*)d_ws;
    float*  h     = (float*)wp;                             // always (round-1 proven)
    ushort* hb_ws = (ushort*)(wp + WS_H);
    ushort* wlogT = (ushort*)(wp + WS_H + WS_HB);

    // ---- d_out scratch pool (all dead before final logit write) ----
    char* op = (char*)d_out;
    auto take = [](char*& p, size_t bytes) {
        char* r = p; p += (bytes + 255) & ~(size_t)255; return r;
    };
    ushort* memb  = (ushort*)take(op, (size_t)MROWS * 512 * 2);
    ushort* wsq   = (ushort*)take(op, 48ull * SQW * 2);
    ushort* w1T   = (ushort*)take(op, 6ull * 1048576 * 2);
    ushort* w2T   = (ushort*)take(op, 6ull * 1048576 * 2);
    float*  kall  = (float*)take(op, 6ull * MROWS * 512 * 4);
    float*  vall  = (float*)take(op, 6ull * MROWS * 512 * 4);
    float*  qq    = (float*)take(op, 3 * ROWB * 4);
    float*  kk    = qq + ROWB;
    float*  vv    = kk + ROWB;
    ushort* attb  = (ushort*)take(op, ROWB * 2);
    float*  proj  = (float*)take(op, ROWB * 4);
    ushort* ffhb  = (ushort*)take(op, (size_t)NROWS * 2048 * 2);
    ushort* hb    = wsBig ? hb_ws : (ushort*)take(op, ROWB * 2);
    const size_t KVOFF = (size_t)MROWS * D_MODEL;

    // ---- prepack: weights -> transposed bf16; memory -> bf16 ----
    Ptr8 ps;
    ps.p[0] = sa_qw; ps.p[1] = sa_kw; ps.p[2] = sa_vw; ps.p[3] = sa_ow;
    ps.p[4] = ca_qw; ps.p[5] = ca_kw; ps.p[6] = ca_vw; ps.p[7] = ca_ow;
    wtrans_sq<<<dim3(256, 48), 256, 0, stream>>>(ps, wsq);
    wtrans_rect<<<dim3(1024, 1, 6), 256, 0, stream>>>(ff_w1, w1T, 512, 2048);
    wtrans_rect<<<dim3(1024, 1, 6), 256, 0, stream>>>(ff_w2, w2T, 2048, 512);
    if (wsBig)
        wtrans_rect<<<dim3(16000, 1, 1), 256, 0, stream>>>(logit_w, wlogT, 512, 32000);
    convb<<<(MROWS * 512) / 2048, 256, 0, stream>>>(memory, memb);

    embed_kernel<<<NROWS, 128, 0, stream>>>(x, emb, pos, h, hb);

    // all 6 layers' cross-attn K/V from constant memory, one launch
    bgemm_kv<64, 64><<<dim3(MROWS / 64, 8, 2 * NLAYER), 256, 0, stream>>>(
        memb, wsq + 30ull * SQW, ca_kb, kall,
              wsq + 36ull * SQW, ca_vb, vall, MROWS, 512, 512);

    const dim3 gattn(SEQ, NHEAD, BATCH);
    const dim3 g512(NROWS / 32, 8, 1);         // 512 blocks (32x64 tiles)
    const dim3 gqkv(NROWS / 64, 8, 3);         // 768 blocks (64x64 tiles)

    for (int l = 0; l < NLAYER; ++l) {
        const size_t b1 = (size_t)l * D_MODEL;
        // ---- masked self-attention ----
        bgemm<64, 64><<<gqkv, 256, 0, stream>>>(hb,
            wsq + (size_t)(0 * 6 + l) * SQW, sa_qb + b1, qq, nullptr,
            wsq + (size_t)(1 * 6 + l) * SQW, sa_kb + b1, kk, nullptr,
            wsq + (size_t)(2 * 6 + l) * SQW, sa_vb + b1, vv, nullptr,
            NROWS, 512, 512, 0);
        attn_kernel<<<gattn, 256, 0, stream>>>(qq, kk, vv, attb, SEQ, 1);
        bgemm<32, 64><<<g512, 256, 0, stream>>>(attb,
            wsq + (size_t)(3 * 6 + l) * SQW, sa_ob + b1, proj, nullptr,
            wsq + (size_t)(3 * 6 + l) * SQW, sa_ob + b1, proj, nullptr,
            wsq + (size_t)(3 * 6 + l) * SQW, sa_ob + b1, proj, nullptr,
            NROWS, 512, 512, 0);
        ln_kernel<<<NROWS, 256, 0, stream>>>(proj, h, sa_lng + b1, sa_lnb + b1,
                                             h, hb, 1e-8f);
        // ---- cross-attention over memory (K/V precomputed) ----
        bgemm<32, 64><<<g512, 256, 0, stream>>>(hb,
            wsq + (size_t)(4 * 6 + l) * SQW, ca_qb + b1, qq, nullptr,
            wsq + (size_t)(4 * 6 + l) * SQW, ca_qb + b1, qq, nullptr,
            wsq + (size_t)(4 * 6 + l) * SQW, ca_qb + b1, qq, nullptr,
            NROWS, 512, 512, 0);
        attn_kernel<<<gattn, 256, 0, stream>>>(qq, kall + (size_t)l * KVOFF,
                                               vall + (size_t)l * KVOFF, attb, MEMS, 0);
        bgemm<32, 64><<<g512, 256, 0, stream>>>(attb,
            wsq + (size_t)(7 * 6 + l) * SQW, ca_ob + b1, proj, nullptr,
            wsq + (size_t)(7 * 6 + l) * SQW, ca_ob + b1, proj, nullptr,
            wsq + (size_t)(7 * 6 + l) * SQW, ca_ob + b1, proj, nullptr,
            NROWS, 512, 512, 0);
        ln_kernel<<<NROWS, 256, 0, stream>>>(proj, h, ca_lng + b1, ca_lnb + b1,
                                             h, hb, 1e-8f);
        // ---- feed-forward (ff1 output consumed only by ff2 -> bf16 only) ----
        bgemm<64, 64><<<dim3(NROWS / 64, 2048 / 64, 1), 256, 0, stream>>>(hb,
            w1T + (size_t)l * 1048576, ff_b1 + (size_t)l * 2048, nullptr, ffhb,
            w1T + (size_t)l * 1048576, ff_b1 + (size_t)l * 2048, nullptr, ffhb,
            w1T + (size_t)l * 1048576, ff_b1 + (size_t)l * 2048, nullptr, ffhb,
            NROWS, 512, 2048, 1);
        bgemm<32, 64><<<g512, 256, 0, stream>>>(ffhb,
            w2T + (size_t)l * 1048576, ff_b2 + b1, proj, nullptr,
            w2T + (size_t)l * 1048576, ff_b2 + b1, proj, nullptr,
            w2T + (size_t)l * 1048576, ff_b2 + b1, proj, nullptr,
            NROWS, 2048, 512, 0);
        ln_kernel<<<NROWS, 256, 0, stream>>>(proj, h, ff_lng + b1, ff_lnb + b1,
                                             h, hb, 1e-6f);
    }
    // ---- logits: reads only d_ws-resident operands when bf16 path active ----
    if (wsBig) {
        bgemm<128, 128><<<dim3(NROWS / 128, 32000 / 128, 1), 256, 0, stream>>>(hb,
            wlogT, logit_b, out, nullptr,
            wlogT, logit_b, out, nullptr,
            wlogT, logit_b, out, nullptr, NROWS, 512, 32000, 0);
    } else {
        // fp32 fallback reads h (d_ws) — safe to overwrite all of d_out
        mgemm_f32<<<dim3(NROWS / 128, 32000 / 128, 1), 256, 0, stream>>>(
            h, logit_w, logit_b, out, NROWS, 512, 32000, 0);
    }
}

// Round 4
// 1445.146 us; speedup vs baseline: 3.4774x; 2.4414x over previous
//
#include <hip/hip_runtime.h>
#include <cstdint>

#define D_MODEL 512
#define NHEAD   8
#define DKH     64
#define NLAYER  6
#define BATCH   16
#define SEQ     128
#define MEMS    196
#define NROWS   (BATCH*SEQ)   // 2048
#define MROWS   (BATCH*MEMS)  // 3136
#define SQW     (512*512)
#define SP_SELF 128
#define SP_CROSS 224          // 196 padded to multiple of 32

typedef __attribute__((ext_vector_type(8))) short short8;
typedef __attribute__((ext_vector_type(4))) short short4v;
typedef __attribute__((ext_vector_type(4))) float floatx4;

__device__ __forceinline__ short f2bf(float f) {
    unsigned u = __builtin_bit_cast(unsigned, f);
    u += 0x7fffu + ((u >> 16) & 1u);            // RNE
    return (short)(u >> 16);
}

// async global->LDS, 16B per lane, dest = wave-uniform base + lane*16
#define GLD16(g, l) __builtin_amdgcn_global_load_lds( \
    (const __attribute__((address_space(1))) void*)(g), \
    (__attribute__((address_space(3))) void*)(l), 16, 0, 0)

// ---------------- embedding + positional (fp32 + bf16 mirror) ----------------
__global__ __launch_bounds__(128) void embed_kernel(
    const int* __restrict__ x, const float* __restrict__ emb,
    const float* __restrict__ pos, float* __restrict__ h, ushort* __restrict__ hb)
{
    const int row = blockIdx.x;
    const int s   = row & (SEQ - 1);
    const int tok = x[row];
    const int c   = threadIdx.x * 4;
    const float4 e = *(const float4*)(emb + (size_t)tok * D_MODEL + c);
    const float4 p = *(const float4*)(pos + (size_t)s   * D_MODEL + c);
    float4 o;
    o.x = e.x + p.x; o.y = e.y + p.y; o.z = e.z + p.z; o.w = e.w + p.w;
    *(float4*)(h + (size_t)row * D_MODEL + c) = o;
    const short4v ob = { f2bf(o.x), f2bf(o.y), f2bf(o.z), f2bf(o.w) };
    *(short4v*)(hb + (size_t)row * D_MODEL + c) = ob;
}

// ---------------- weight transpose+convert: Out[n][k] = bf16(In[k][n]) -------
__device__ __forceinline__ void wtrans_tile(
    const float* __restrict__ In, ushort* __restrict__ Out,
    int K, int N, int tk, int tx)
{
    __shared__ ushort t[32][33];
    const int tid = threadIdx.x;
    const int r  = tid >> 3;            // 0..31
    const int c4 = (tid & 7) << 2;      // 0,4,..,28
    const float4 v = *(const float4*)(In + (size_t)(tk * 32 + r) * N + tx * 32 + c4);
    t[c4 + 0][r] = (ushort)f2bf(v.x);
    t[c4 + 1][r] = (ushort)f2bf(v.y);
    t[c4 + 2][r] = (ushort)f2bf(v.z);
    t[c4 + 3][r] = (ushort)f2bf(v.w);
    __syncthreads();
    const short4v o = { (short)t[r][c4], (short)t[r][c4 + 1],
                        (short)t[r][c4 + 2], (short)t[r][c4 + 3] };
    *(short4v*)(Out + (size_t)(tx * 32 + r) * K + tk * 32 + c4) = o;
}

struct Ptr8 { const float* p[8]; };

// all 8 square (512x512) weight families x 6 layers -> wsq[mat][512][512]
__global__ __launch_bounds__(256) void wtrans_sq(Ptr8 ps, ushort* __restrict__ out)
{
    const int mat = blockIdx.y;              // 0..47
    const int a = mat / 6, l = mat - a * 6;
    const float* In = ps.p[a] + (size_t)l * SQW;
    ushort* Out = out + (size_t)mat * SQW;
    const int tx = blockIdx.x & 15, tk = blockIdx.x >> 4;
    wtrans_tile(In, Out, 512, 512, tk, tx);
}

__global__ __launch_bounds__(256) void wtrans_rect(
    const float* __restrict__ in, ushort* __restrict__ out, int K, int N)
{
    const float* In = in + (size_t)blockIdx.z * K * N;
    ushort* Out = out + (size_t)blockIdx.z * K * N;
    const int ntx = N >> 5;
    const int tx = blockIdx.x % ntx, tk = blockIdx.x / ntx;
    wtrans_tile(In, Out, K, N, tk, tx);
}

// fp32 -> bf16 elementwise (memory operand)
__global__ __launch_bounds__(256) void convb(
    const float* __restrict__ in, ushort* __restrict__ out)
{
    const size_t i = ((size_t)blockIdx.x * 256 + threadIdx.x) * 8;
    const float4 a = *(const float4*)(in + i);
    const float4 b = *(const float4*)(in + i + 4);
    const short8 o = { f2bf(a.x), f2bf(a.y), f2bf(a.z), f2bf(a.w),
                       f2bf(b.x), f2bf(b.y), f2bf(b.z), f2bf(b.w) };
    *(short8*)(out + i) = o;
}

// ---- per-head V transpose: V bf16 [b*Sk+s][512] -> VT [(b*8+h)*64+d][SP] ----
// zero-fills s in [Sk, SP)  (P is 0 there, but MFMA needs finite operands)
__global__ __launch_bounds__(256) void vtrans_kernel(
    const ushort* __restrict__ V, ushort* __restrict__ VT,
    int Sk, int SP, size_t lsV, size_t lsT)
{
    const int bh = blockIdx.x;               // b*8+h
    const int s0 = blockIdx.y << 5;
    const int l  = blockIdx.z >> 1;
    const int d0 = (blockIdx.z & 1) << 5;
    const int b = bh >> 3, hh = bh & 7;
    const ushort* Vl = V + (size_t)l * lsV;
    ushort* Tl = VT + (size_t)l * lsT;
    __shared__ ushort t[32][36];
    const int tid = threadIdx.x;
    {
        const int sl = tid >> 3, d4 = (tid & 7) << 2;
        short4v v = {0, 0, 0, 0};
        const int s = s0 + sl;
        if (s < Sk)
            v = *(const short4v*)&Vl[(size_t)(b * Sk + s) * D_MODEL + hh * DKH + d0 + d4];
        t[sl][d4 + 0] = (ushort)v[0];
        t[sl][d4 + 1] = (ushort)v[1];
        t[sl][d4 + 2] = (ushort)v[2];
        t[sl][d4 + 3] = (ushort)v[3];
    }
    __syncthreads();
    {
        const int dl = tid >> 3, s4 = (tid & 7) << 2;
        const short4v o = { (short)t[s4 + 0][dl], (short)t[s4 + 1][dl],
                            (short)t[s4 + 2][dl], (short)t[s4 + 3][dl] };
        *(short4v*)&Tl[((size_t)(bh * 64) + d0 + dl) * SP + s0 + s4] = o;
    }
}

// ---------------- bf16 GEMM: C = A(MxK,bf16) @ WT(NxK,bf16)^T + bias ---------
// global_load_lds staging (16B/lane, source pre-swizzled), double-buffered LDS,
// ONE barrier per K-step (stage next || compute current). 256 thr = 4 waves.
template<int BM, int BN>
__device__ __forceinline__ void bgemm_core(
    const ushort* __restrict__ A, const ushort* __restrict__ WT,
    const float* __restrict__ bias, float* __restrict__ Cf,
    ushort* __restrict__ Cb, int M, int K, int N, int relu)
{
    constexpr int WM = (BM >= 64) ? 2 : 1;
    constexpr int WN = 4 / WM;
    constexpr int RM = BM / (WM * 16);
    constexpr int RN = BN / (WN * 16);
    constexpr int SA = BM / 16;          // 1KB stage slots for A
    constexpr int SB = BN / 16;
    constexpr int ST = SA + SB;

    __shared__ __align__(16) ushort As[2][BM * 32];
    __shared__ __align__(16) ushort Bs[2][BN * 32];

    const int tid  = threadIdx.x;
    const int lane = tid & 63, wave = tid >> 6;
    const int m0 = blockIdx.x * BM, n0 = blockIdx.y * BN;
    const int wm = (wave % WM) * (16 * RM);
    const int wn = (wave / WM) * (16 * RN);
    const int fm = lane & 15, fq = lane >> 4;
    const int rdoff = ((fq ^ ((fm >> 2) & 3)) << 3);     // swizzled read chunk

    const int srow = lane >> 2;
    const int soff = (((lane & 3) ^ ((lane >> 4) & 3)) << 3);

    floatx4 acc[RM][RN] = {};

    auto stage = [&](int buf, int k0) {
        #pragma unroll
        for (int s = 0; s < ST; ++s) {
            if ((s & 3) != wave) continue;     // wave-uniform predicate
            if (s < SA)
                GLD16(A + (size_t)(m0 + s * 16 + srow) * K + k0 + soff,
                      &As[buf][s * 512]);
            else
                GLD16(WT + (size_t)(n0 + (s - SA) * 16 + srow) * K + k0 + soff,
                      &Bs[buf][(s - SA) * 512]);
        }
    };

    stage(0, 0);
    __syncthreads();                       // drains vmcnt(0)
    const int NT = K >> 5;
    int cur = 0;
    for (int t = 0; t < NT; ++t) {
        if (t + 1 < NT) stage(cur ^ 1, (t + 1) << 5);
        short8 af[RM], bfr[RN];
        #pragma unroll
        for (int i = 0; i < RM; ++i)
            af[i] = *(const short8*)&As[cur][(wm + i * 16 + fm) * 32 + rdoff];
        #pragma unroll
        for (int j = 0; j < RN; ++j)
            bfr[j] = *(const short8*)&Bs[cur][(wn + j * 16 + fm) * 32 + rdoff];
        #pragma unroll
        for (int i = 0; i < RM; ++i)
            #pragma unroll
            for (int j = 0; j < RN; ++j)
                acc[i][j] = __builtin_amdgcn_mfma_f32_16x16x32_bf16(
                                af[i], bfr[j], acc[i][j], 0, 0, 0);
        __syncthreads();                   // stage complete + frag reads done
        cur ^= 1;
    }

    // epilogue: C/D layout col=lane&15, row=(lane>>4)*4+reg
    #pragma unroll
    for (int j = 0; j < RN; ++j) {
        const int col = n0 + wn + j * 16 + fm;
        const float bv = bias[col];
        #pragma unroll
        for (int i = 0; i < RM; ++i) {
            const int r0 = m0 + wm + i * 16 + fq * 4;
            #pragma unroll
            for (int r = 0; r < 4; ++r) {
                float v = acc[i][j][r] + bv;
                if (relu) v = fmaxf(v, 0.f);
                const size_t idx = (size_t)(r0 + r) * N + col;
                if (Cf) Cf[idx] = v;
                if (Cb) Cb[idx] = (ushort)f2bf(v);
            }
        }
    }
}

// up-to-3 fused GEMMs sharing A, selected by blockIdx.z
template<int BM, int BN>
__global__ __launch_bounds__(256) void bgemm(
    const ushort* __restrict__ A,
    const ushort* W0, const float* b0, float* F0, ushort* O0,
    const ushort* W1, const float* b1, float* F1, ushort* O1,
    const ushort* W2, const float* b2, float* F2, ushort* O2,
    int M, int K, int N, int relu)
{
    const ushort* W; const float* bb; float* F; ushort* Ob;
    if (blockIdx.z == 0)      { W = W0; bb = b0; F = F0; Ob = O0; }
    else if (blockIdx.z == 1) { W = W1; bb = b1; F = F1; Ob = O1; }
    else                      { W = W2; bb = b2; F = F2; Ob = O2; }
    bgemm_core<BM, BN>(A, W, bb, F, Ob, M, K, N, relu);
}

// all-layer cross-attn K/V projections in ONE launch (z = 2*layer + isV)
// outputs bf16 directly
template<int BM, int BN>
__global__ __launch_bounds__(256) void bgemm_kv(
    const ushort* __restrict__ A,
    const ushort* Wk, const float* bk, ushort* Ck,
    const ushort* Wv, const float* bv, ushort* Cv,
    int M, int K, int N)
{
    const int l = blockIdx.z >> 1;
    const bool isv = blockIdx.z & 1;
    const ushort* W = (isv ? Wv : Wk) + (size_t)l * K * N;
    const float* bb = (isv ? bv : bk) + (size_t)l * N;
    ushort* C       = (isv ? Cv : Ck) + (size_t)l * M * N;
    bgemm_core<BM, BN>(A, W, bb, (float*)nullptr, C, M, K, N, 0);
}

// ---------------- round-1-proven fp32 GEMM (logit fallback if ws small) ------
__global__ __launch_bounds__(256) void mgemm_f32(
    const float* __restrict__ A, const float* __restrict__ W,
    const float* __restrict__ bias, float* __restrict__ C,
    int M, int K, int N, int relu)
{
    constexpr int BM = 128, BN = 128;
    constexpr int RM = BM / 32, RN = BN / 32;
    constexpr int TPR = 256 / BM;
    constexpr int ANV = BM / 32;
    constexpr int BACT = 2 * BN;

    __shared__ __align__(16) short As[BM * 32];
    __shared__ __align__(16) short Bs[BN * 32];

    const int tid = threadIdx.x;
    const int m0 = blockIdx.x * BM, n0 = blockIdx.y * BN;
    const int lane = tid & 63;
    const int wave = tid >> 6;
    const int wm = (wave >> 1) * (BM / 2), wn = (wave & 1) * (BN / 2);
    const int fm = lane & 15;
    const int fq = lane >> 4;
    const int fsw = ((fq ^ ((fm >> 2) & 3)) << 3);

    floatx4 acc[RM][RN] = {};

    const int ar = tid / TPR;
    const int ac = (tid % TPR) * (32 / TPR);
    const int asw = (ar >> 2) & 3;
    const int kb = (tid / (BN / 4)) * 4;
    const int nb = (tid % (BN / 4)) * 4;
    const int bsw = (((kb >> 3) ^ ((nb >> 2) & 3)) << 3) + (kb & 7);

    const int arow = min(m0 + ar, M - 1);
    const float* Ap = A + (size_t)arow * K + ac;
    const float* Wp = W + (size_t)kb * N + n0 + nb;

    for (int k0 = 0; k0 < K; k0 += 32) {
        float4 av[ANV];
        #pragma unroll
        for (int i = 0; i < ANV; ++i)
            av[i] = *(const float4*)(Ap + k0 + 4 * i);
        float4 w0 = {0,0,0,0}, w1 = {0,0,0,0}, w2 = {0,0,0,0}, w3 = {0,0,0,0};
        if (tid < BACT) {
            w0 = *(const float4*)(Wp + (size_t)(k0    ) * N);
            w1 = *(const float4*)(Wp + (size_t)(k0 + 1) * N);
            w2 = *(const float4*)(Wp + (size_t)(k0 + 2) * N);
            w3 = *(const float4*)(Wp + (size_t)(k0 + 3) * N);
        }
        __syncthreads();
        #pragma unroll
        for (int c = 0; c < ANV / 2; ++c) {
            const float4 lo = av[2 * c], hi = av[2 * c + 1];
            const short8 s8 = { f2bf(lo.x), f2bf(lo.y), f2bf(lo.z), f2bf(lo.w),
                                f2bf(hi.x), f2bf(hi.y), f2bf(hi.z), f2bf(hi.w) };
            *(short8*)&As[ar * 32 + ((((ac >> 3) + c) ^ asw) << 3)] = s8;
        }
        if (tid < BACT) {
            const float wt[4][4] = {{w0.x, w0.y, w0.z, w0.w},
                                    {w1.x, w1.y, w1.z, w1.w},
                                    {w2.x, w2.y, w2.z, w2.w},
                                    {w3.x, w3.y, w3.z, w3.w}};
            #pragma unroll
            for (int j = 0; j < 4; ++j) {
                const short4v bw = { f2bf(wt[0][j]), f2bf(wt[1][j]),
                                     f2bf(wt[2][j]), f2bf(wt[3][j]) };
                *(short4v*)&Bs[(nb + j) * 32 + bsw] = bw;
            }
        }
        __syncthreads();
        short8 af[RM], bfrag[RN];
        #pragma unroll
        for (int i = 0; i < RM; ++i)
            af[i] = *(const short8*)&As[(wm + i * 16 + fm) * 32 + fsw];
        #pragma unroll
        for (int j = 0; j < RN; ++j)
            bfrag[j] = *(const short8*)&Bs[(wn + j * 16 + fm) * 32 + fsw];
        #pragma unroll
        for (int i = 0; i < RM; ++i)
            #pragma unroll
            for (int j = 0; j < RN; ++j)
                acc[i][j] = __builtin_amdgcn_mfma_f32_16x16x32_bf16(
                                af[i], bfrag[j], acc[i][j], 0, 0, 0);
    }
    #pragma unroll
    for (int j = 0; j < RN; ++j) {
        const int col = n0 + wn + j * 16 + fm;
        const float bv = bias[col];
        #pragma unroll
        for (int i = 0; i < RM; ++i) {
            const int r0 = m0 + wm + i * 16 + fq * 4;
            #pragma unroll
            for (int r = 0; r < 4; ++r) {
                const int row = r0 + r;
                if (row < M) {
                    float v = acc[i][j][r] + bv;
                    if (relu) v = fmaxf(v, 0.f);
                    C[(size_t)row * N + col] = v;
                }
            }
        }
    }
}

// ---------------- MFMA flash attention: block = (16 q-rows, head, batch) -----
// Q,K bf16 row-major [rows][512]; VT bf16 [(b*8+h)*64+d][SP]; O bf16.
// S = Q@K^T/64 (+causal mask) -> LDS fp32 -> softmax (16 thr/row) ->
// P bf16 LDS -> O = P@V via VT frags -> scale by 1/sum.
__global__ __launch_bounds__(256) void attn_mfma(
    const ushort* __restrict__ Q, const ushort* __restrict__ K,
    const ushort* __restrict__ VT, ushort* __restrict__ O,
    int Sk, int SP, int causal)
{
    const int qt = blockIdx.x;           // q-tile (16 rows)
    const int hh = blockIdx.y;
    const int b  = blockIdx.z;
    const int tid = threadIdx.x;
    const int lane = tid & 63, wave = tid >> 6;
    const int fm = lane & 15, fq = lane >> 4;

    __shared__ __align__(16) float  Slds[16 * 225];
    __shared__ __align__(16) ushort Plds[16 * 232];
    __shared__ float invs[16];

    const int KT   = (Sk + 15) >> 4;     // 8 (self) / 13 (cross)
    const int KT16 = KT << 4;            // 128 / 208
    const int CH   = SP >> 5;            // 4 / 7

    // init: S = -1e30 (skipped causal tiles), P = 0 (padded k range)
    for (int j = tid; j < 16 * 225; j += 256) Slds[j] = -1e30f;
    {
        const short8 z = {0,0,0,0,0,0,0,0};
        for (int j = tid; j < (16 * 232) / 8; j += 256) ((short8*)Plds)[j] = z;
    }
    // Q fragments (A operand): row=fm, 8 consecutive d at fq*8 (+32 for chunk 1)
    const int q0 = qt << 4;
    const size_t qbase = ((size_t)(b * SEQ) + q0 + fm) * D_MODEL + hh * DKH;
    const short8 qf0 = *(const short8*)&Q[qbase + fq * 8];
    const short8 qf1 = *(const short8*)&Q[qbase + 32 + fq * 8];
    __syncthreads();

    // ---- QK^T: wave w handles k-tiles w, w+4, ... (causal tiles skipped) ----
    const int KTeff = causal ? min(KT, qt + 1) : KT;
    for (int kt = wave; kt < KTeff; kt += 4) {
        const int krow = kt * 16 + fm;
        const size_t kbase =
            ((size_t)(b * Sk) + min(krow, Sk - 1)) * D_MODEL + hh * DKH;
        const short8 kf0 = *(const short8*)&K[kbase + fq * 8];
        const short8 kf1 = *(const short8*)&K[kbase + 32 + fq * 8];
        floatx4 s = {0.f, 0.f, 0.f, 0.f};
        s = __builtin_amdgcn_mfma_f32_16x16x32_bf16(qf0, kf0, s, 0, 0, 0);
        s = __builtin_amdgcn_mfma_f32_16x16x32_bf16(qf1, kf1, s, 0, 0, 0);
        // C layout: col(k)=fm, row(q)=fq*4+r
        #pragma unroll
        for (int r = 0; r < 4; ++r) {
            const int qrow = q0 + fq * 4 + r;
            const int j = kt * 16 + fm;
            const float val = (j >= Sk || (causal && j > qrow))
                              ? -1e30f : s[r] * (1.0f / 64.0f);
            Slds[(fq * 4 + r) * 225 + j] = val;
        }
    }
    __syncthreads();

    // ---- softmax: 16 threads per row (consecutive lanes) ----
    {
        const int row = tid >> 4, c = tid & 15;
        float m = -1e30f;
        for (int j = c; j < KT16; j += 16) m = fmaxf(m, Slds[row * 225 + j]);
        #pragma unroll
        for (int off = 8; off > 0; off >>= 1) m = fmaxf(m, __shfl_xor(m, off));
        float sum = 0.f;
        for (int j = c; j < KT16; j += 16) {
            const float e = __expf(Slds[row * 225 + j] - m);
            Plds[row * 232 + j] = (ushort)f2bf(e);
            sum += e;
        }
        #pragma unroll
        for (int off = 8; off > 0; off >>= 1) sum += __shfl_xor(sum, off);
        if (c == 0) invs[row] = 1.0f / sum;
    }
    __syncthreads();

    // ---- PV: wave w owns output d-tile w (16 cols); A=P frags, B=VT frags ---
    floatx4 o = {0.f, 0.f, 0.f, 0.f};
    const size_t vbase = ((size_t)(b * 8 + hh) * 64 + wave * 16 + fm) * SP;
    for (int ch = 0; ch < CH; ++ch) {
        const short8 pf = *(const short8*)&Plds[fm * 232 + ch * 32 + fq * 8];
        const short8 vf = *(const short8*)&VT[vbase + ch * 32 + fq * 8];
        o = __builtin_amdgcn_mfma_f32_16x16x32_bf16(pf, vf, o, 0, 0, 0);
    }
    #pragma unroll
    for (int r = 0; r < 4; ++r) {
        const int qrow = fq * 4 + r;
        const float val = o[r] * invs[qrow];
        O[((size_t)(b * SEQ) + q0 + qrow) * D_MODEL + hh * DKH + wave * 16 + fm]
            = (ushort)f2bf(val);
    }
}

// ---------------- residual add + layernorm: Y = LN(X + R)*g + b (+bf16 mirror)
__global__ __launch_bounds__(256) void ln_kernel(
    const float* __restrict__ X, const float* __restrict__ R,
    const float* __restrict__ g, const float* __restrict__ bb,
    float* __restrict__ Y, ushort* __restrict__ Yb, float eps)
{
    const int row = blockIdx.x;
    const int tid = threadIdx.x;
    const int lane = tid & 63, wave = tid >> 6;
    __shared__ float wred[8];
    const size_t base = (size_t)row * D_MODEL;
    const float x0 = X[base + tid]       + R[base + tid];
    const float x1 = X[base + 256 + tid] + R[base + 256 + tid];
    float sm = x0 + x1;
    #pragma unroll
    for (int off = 32; off > 0; off >>= 1) sm += __shfl_xor(sm, off);
    if (lane == 0) wred[wave] = sm;
    __syncthreads();
    const float mu = (wred[0] + wred[1] + wred[2] + wred[3]) * (1.0f / D_MODEL);
    const float d0 = x0 - mu, d1 = x1 - mu;
    float vs = d0 * d0 + d1 * d1;
    #pragma unroll
    for (int off = 32; off > 0; off >>= 1) vs += __shfl_xor(vs, off);
    if (lane == 0) wred[4 + wave] = vs;
    __syncthreads();
    const float var  = (wred[4] + wred[5] + wred[6] + wred[7]) * (1.0f / D_MODEL);
    const float rstd = rsqrtf(var + eps);
    const float y0 = d0 * rstd * g[tid]       + bb[tid];
    const float y1 = d1 * rstd * g[256 + tid] + bb[256 + tid];
    Y[base + tid]       = y0;
    Y[base + 256 + tid] = y1;
    Yb[base + tid]       = (ushort)f2bf(y0);
    Yb[base + 256 + tid] = (ushort)f2bf(y1);
}

extern "C" void kernel_launch(void* const* d_in, const int* in_sizes, int n_in,
                              void* d_out, int out_size, void* d_ws, size_t ws_size,
                              hipStream_t stream)
{
    const int*   x      = (const int*)  d_in[0];
    const float* memory = (const float*)d_in[1];
    // d_in[2] = mask — exactly causal tril; handled analytically
    const float* emb    = (const float*)d_in[3];
    const float* pos    = (const float*)d_in[4];
    const float* sa_qw  = (const float*)d_in[5];
    const float* sa_kw  = (const float*)d_in[6];
    const float* sa_vw  = (const float*)d_in[7];
    const float* sa_ow  = (const float*)d_in[8];
    const float* sa_qb  = (const float*)d_in[9];
    const float* sa_kb  = (const float*)d_in[10];
    const float* sa_vb  = (const float*)d_in[11];
    const float* sa_ob  = (const float*)d_in[12];
    const float* sa_lnb = (const float*)d_in[13];
    const float* sa_lng = (const float*)d_in[14];
    const float* ca_qw  = (const float*)d_in[15];
    const float* ca_kw  = (const float*)d_in[16];
    const float* ca_vw  = (const float*)d_in[17];
    const float* ca_ow  = (const float*)d_in[18];
    const float* ca_qb  = (const float*)d_in[19];
    const float* ca_kb  = (const float*)d_in[20];
    const float* ca_vb  = (const float*)d_in[21];
    const float* ca_ob  = (const float*)d_in[22];
    const float* ca_lnb = (const float*)d_in[23];
    const float* ca_lng = (const float*)d_in[24];
    const float* ff_w1  = (const float*)d_in[25];
    const float* ff_b1  = (const float*)d_in[26];
    const float* ff_w2  = (const float*)d_in[27];
    const float* ff_b2  = (const float*)d_in[28];
    const float* ff_lng = (const float*)d_in[29];
    const float* ff_lnb = (const float*)d_in[30];
    const float* logit_w= (const float*)d_in[31];
    const float* logit_b= (const float*)d_in[32];

    float* out = (float*)d_out;
    const size_t ROWB = (size_t)NROWS * D_MODEL;            // 1M elems

    // ---- d_ws: h (proven) + optionally {hb, wlogT} (read by final logit) ----
    const size_t WS_H    = ROWB * 4;                        // 4 MB
    const size_t WS_HB   = ROWB * 2;                        // 2 MB
    const size_t WS_WLOG = 512ull * 32000 * 2;              // 32.8 MB
    const bool wsBig = ws_size >= WS_H + WS_HB + WS_WLOG + 1024;

    char* wp = (char*)d_ws;
    float*  h     = (float*)wp;
    ushort* hb_ws = (ushort*)(wp + WS_H);
    ushort* wlogT = (ushort*)(wp + WS_H + WS_HB);

    // ---- d_out scratch pool (all dead before final logit write) ----
    char* op = (char*)d_out;
    auto take = [](char*& p, size_t bytes) {
        char* r = p; p += (bytes + 255) & ~(size_t)255; return r;
    };
    const size_t KVOFF  = (size_t)MROWS * D_MODEL;          // per-layer K/V elems
    const size_t VTOFF  = (size_t)BATCH * NHEAD * DKH * SP_CROSS; // per-layer VT
    ushort* memb  = (ushort*)take(op, (size_t)MROWS * 512 * 2);
    ushort* wsq   = (ushort*)take(op, 48ull * SQW * 2);
    ushort* w1T   = (ushort*)take(op, 6ull * 1048576 * 2);
    ushort* w2T   = (ushort*)take(op, 6ull * 1048576 * 2);
    ushort* kallb = (ushort*)take(op, 6ull * KVOFF * 2);
    ushort* vallb = (ushort*)take(op, 6ull * KVOFF * 2);
    ushort* vallT = (ushort*)take(op, 6ull * VTOFF * 2);
    ushort* qbb   = (ushort*)take(op, ROWB * 2);
    ushort* kbb   = (ushort*)take(op, ROWB * 2);
    ushort* vbb   = (ushort*)take(op, ROWB * 2);
    ushort* vbT   = (ushort*)take(op, (size_t)BATCH * NHEAD * DKH * SP_SELF * 2);
    ushort* attb  = (ushort*)take(op, ROWB * 2);
    float*  proj  = (float*)take(op, ROWB * 4);
    ushort* ffhb  = (ushort*)take(op, (size_t)NROWS * 2048 * 2);
    ushort* hb    = wsBig ? hb_ws : (ushort*)take(op, ROWB * 2);

    // ---- prepack: weights -> transposed bf16; memory -> bf16 ----
    Ptr8 ps;
    ps.p[0] = sa_qw; ps.p[1] = sa_kw; ps.p[2] = sa_vw; ps.p[3] = sa_ow;
    ps.p[4] = ca_qw; ps.p[5] = ca_kw; ps.p[6] = ca_vw; ps.p[7] = ca_ow;
    wtrans_sq<<<dim3(256, 48), 256, 0, stream>>>(ps, wsq);
    wtrans_rect<<<dim3(1024, 1, 6), 256, 0, stream>>>(ff_w1, w1T, 512, 2048);
    wtrans_rect<<<dim3(1024, 1, 6), 256, 0, stream>>>(ff_w2, w2T, 2048, 512);
    if (wsBig)
        wtrans_rect<<<dim3(16000, 1, 1), 256, 0, stream>>>(logit_w, wlogT, 512, 32000);
    convb<<<(MROWS * 512) / 2048, 256, 0, stream>>>(memory, memb);

    embed_kernel<<<NROWS, 128, 0, stream>>>(x, emb, pos, h, hb);

    // all 6 layers' cross-attn K/V (bf16) + V transpose, once
    bgemm_kv<64, 64><<<dim3(MROWS / 64, 8, 2 * NLAYER), 256, 0, stream>>>(
        memb, wsq + 30ull * SQW, ca_kb, kallb,
              wsq + 36ull * SQW, ca_vb, vallb, MROWS, 512, 512);
    vtrans_kernel<<<dim3(128, SP_CROSS / 32, 2 * NLAYER), 256, 0, stream>>>(
        vallb, vallT, MEMS, SP_CROSS, KVOFF, VTOFF);

    const dim3 gattn(SEQ / 16, NHEAD, BATCH);   // 1024 blocks
    const dim3 g512(NROWS / 32, 8, 1);          // 512 blocks (32x64 tiles)
    const dim3 gqkv(NROWS / 64, 8, 3);          // 768 blocks (64x64 tiles)

    for (int l = 0; l < NLAYER; ++l) {
        const size_t b1 = (size_t)l * D_MODEL;
        // ---- masked self-attention ----
        bgemm<64, 64><<<gqkv, 256, 0, stream>>>(hb,
            wsq + (size_t)(0 * 6 + l) * SQW, sa_qb + b1, nullptr, qbb,
            wsq + (size_t)(1 * 6 + l) * SQW, sa_kb + b1, nullptr, kbb,
            wsq + (size_t)(2 * 6 + l) * SQW, sa_vb + b1, nullptr, vbb,
            NROWS, 512, 512, 0);
        vtrans_kernel<<<dim3(128, SP_SELF / 32, 2), 256, 0, stream>>>(
            vbb, vbT, SEQ, SP_SELF, 0, 0);
        attn_mfma<<<gattn, 256, 0, stream>>>(qbb, kbb, vbT, attb, SEQ, SP_SELF, 1);
        bgemm<32, 64><<<g512, 256, 0, stream>>>(attb,
            wsq + (size_t)(3 * 6 + l) * SQW, sa_ob + b1, proj, nullptr,
            wsq + (size_t)(3 * 6 + l) * SQW, sa_ob + b1, proj, nullptr,
            wsq + (size_t)(3 * 6 + l) * SQW, sa_ob + b1, proj, nullptr,
            NROWS, 512, 512, 0);
        ln_kernel<<<NROWS, 256, 0, stream>>>(proj, h, sa_lng + b1, sa_lnb + b1,
                                             h, hb, 1e-8f);
        // ---- cross-attention over memory (K/V + VT precomputed) ----
        bgemm<32, 64><<<g512, 256, 0, stream>>>(hb,
            wsq + (size_t)(4 * 6 + l) * SQW, ca_qb + b1, nullptr, qbb,
            wsq + (size_t)(4 * 6 + l) * SQW, ca_qb + b1, nullptr, qbb,
            wsq + (size_t)(4 * 6 + l) * SQW, ca_qb + b1, nullptr, qbb,
            NROWS, 512, 512, 0);
        attn_mfma<<<gattn, 256, 0, stream>>>(qbb, kallb + l * KVOFF,
                                             vallT + l * VTOFF, attb,
                                             MEMS, SP_CROSS, 0);
        bgemm<32, 64><<<g512, 256, 0, stream>>>(attb,
            wsq + (size_t)(7 * 6 + l) * SQW, ca_ob + b1, proj, nullptr,
            wsq + (size_t)(7 * 6 + l) * SQW, ca_ob + b1, proj, nullptr,
            wsq + (size_t)(7 * 6 + l) * SQW, ca_ob + b1, proj, nullptr,
            NROWS, 512, 512, 0);
        ln_kernel<<<NROWS, 256, 0, stream>>>(proj, h, ca_lng + b1, ca_lnb + b1,
                                             h, hb, 1e-8f);
        // ---- feed-forward ----
        bgemm<64, 64><<<dim3(NROWS / 64, 2048 / 64, 1), 256, 0, stream>>>(hb,
            w1T + (size_t)l * 1048576, ff_b1 + (size_t)l * 2048, nullptr, ffhb,
            w1T + (size_t)l * 1048576, ff_b1 + (size_t)l * 2048, nullptr, ffhb,
            w1T + (size_t)l * 1048576, ff_b1 + (size_t)l * 2048, nullptr, ffhb,
            NROWS, 512, 2048, 1);
        bgemm<32, 64><<<g512, 256, 0, stream>>>(ffhb,
            w2T + (size_t)l * 1048576, ff_b2 + b1, proj, nullptr,
            w2T + (size_t)l * 1048576, ff_b2 + b1, proj, nullptr,
            w2T + (size_t)l * 1048576, ff_b2 + b1, proj, nullptr,
            NROWS, 2048, 512, 0);
        ln_kernel<<<NROWS, 256, 0, stream>>>(proj, h, ff_lng + b1, ff_lnb + b1,
                                             h, hb, 1e-6f);
    }
    // ---- logits ----
    if (wsBig) {
        bgemm<128, 128><<<dim3(NROWS / 128, 32000 / 128, 1), 256, 0, stream>>>(hb,
            wlogT, logit_b, out, nullptr,
            wlogT, logit_b, out, nullptr,
            wlogT, logit_b, out, nullptr, NROWS, 512, 32000, 0);
    } else {
        mgemm_f32<<<dim3(NROWS / 128, 32000 / 128, 1), 256, 0, stream>>>(
            h, logit_w, logit_b, out, NROWS, 512, 32000, 0);
    }
}